// Round 7
// baseline (305.633 us; speedup 1.0000x reference)
//
#include <hip/hip_runtime.h>

typedef __bf16 bf16;
typedef __bf16 bf16x8 __attribute__((ext_vector_type(8)));
typedef _Float16 f16;
typedef _Float16 f16x8 __attribute__((ext_vector_type(8)));
typedef float f32x4 __attribute__((ext_vector_type(4)));

#define SCALE 0.125f
#define AP 72   // bf16 LDS row stride for attn/ckv tiles (64 + 8 pad)
#define CT 128  // bf16 LDS row stride for 128-wide C-tile (aliases As|Bs exactly, 32KB)

// ---------------------------------------------------------------------------
// async global->LDS, 16B per lane (wave-uniform LDS base + lane*16 layout)
// ---------------------------------------------------------------------------
__device__ __forceinline__ void async_ld16(const void* g, void* l) {
  __builtin_amdgcn_global_load_lds((const __attribute__((address_space(1))) void*)g,
                                   (__attribute__((address_space(3))) void*)l, 16, 0, 0);
}

// ---------------------------------------------------------------------------
// Pass 0: convert/split inputs (float4-vectorized).
//   xsplit : 8192 x 2048 bf16  [x_hi | x_lo]
//   wsplit : 3072 x 2048 bf16  [w_hi | w_lo]
//   wo16   : 1024 x 1024 f16
// ---------------------------------------------------------------------------
__global__ __launch_bounds__(256) void k_convert(
    const float* __restrict__ x, const float* __restrict__ wqkv, const float* __restrict__ wo,
    bf16* __restrict__ xsplit, bf16* __restrict__ wsplit, f16* __restrict__ wo16)
{
  const int N1 = 2097152, N2 = 786432, N3 = 262144;  // in float4 units
  const int i = blockIdx.x * 256 + threadIdx.x;
  if (i < N1) {
    f32x4 v = ((const f32x4*)x)[i];
    int e = i * 4, m = e >> 10, c = e & 1023;
    bf16 hi[4], lo[4];
#pragma unroll
    for (int u = 0; u < 4; ++u) { hi[u] = (bf16)v[u]; lo[u] = (bf16)(v[u] - (float)hi[u]); }
    *(ulong1*)&xsplit[(size_t)m * 2048 + c] = *(ulong1*)hi;
    *(ulong1*)&xsplit[(size_t)m * 2048 + 1024 + c] = *(ulong1*)lo;
  } else if (i < N1 + N2) {
    int j = i - N1;
    f32x4 v = ((const f32x4*)wqkv)[j];
    int e = j * 4, n = e >> 10, c = e & 1023;
    bf16 hi[4], lo[4];
#pragma unroll
    for (int u = 0; u < 4; ++u) { hi[u] = (bf16)v[u]; lo[u] = (bf16)(v[u] - (float)hi[u]); }
    *(ulong1*)&wsplit[(size_t)n * 2048 + c] = *(ulong1*)hi;
    *(ulong1*)&wsplit[(size_t)n * 2048 + 1024 + c] = *(ulong1*)lo;
  } else if (i < N1 + N2 + N3) {
    int j = i - N1 - N2;
    f32x4 v = ((const f32x4*)wo)[j];
    f16 h[4];
#pragma unroll
    for (int u = 0; u < 4; ++u) h[u] = (f16)v[u];
    *(ulong1*)&wo16[(size_t)j * 4] = *(ulong1*)h;
  }
}

// ---------------------------------------------------------------------------
// Pass 1: QKV GEMM, C[m][n] = sum_k A'[m][k] * B'[n][k]
//   Q cols (n<1024):  1-term bf16, BK=64, 2 LDS tiles
//   K/V cols       :  FUSED 3-term split (xh*wh + xl*wh + xh*wl), BK=32,
//                     4 LDS tiles; swizzle f(row)=(row>>1)&3 so each 8-lane
//                     service group of a b128 frag read covers all 32 banks
//                     (R6's f(row)=row&3 left a 2-way conflict on every read).
// Epilogue: C-tile round-trip through the 32KB smem alias, 128B-run stores.
// ---------------------------------------------------------------------------
__global__ __launch_bounds__(256) void k_gemm_qkv(
    const bf16* __restrict__ A, const bf16* __restrict__ B,
    bf16* __restrict__ Qws, bf16* __restrict__ Kws, bf16* __restrict__ Vws)
{
  __shared__ char smem[32768];
  const int tid = threadIdx.x;
  const int wave = tid >> 6, lane = tid & 63;
  const int quad = lane >> 4, l16 = lane & 15;
  // heavy K/V blocks first, light Q blocks last -> smaller tail
  const int bxr = (blockIdx.x < 16) ? (blockIdx.x + 8) : (blockIdx.x - 16);
  const int n0 = bxr * 128;
  const int m0 = blockIdx.y * 128;
  const int wm = (wave >> 1) << 6, wn = (wave & 1) << 6;
  const int region = n0 >> 10;  // 0=q, 1=k, 2=v
  f32x4 acc[4][4] = {};

  if (region == 0) {
    // ---------------- Q path: BK=64, 2 tiles ----------------
    bf16* As = (bf16*)smem;          // 128*64
    bf16* Bs = As + 128 * 64;
    const int r8 = lane >> 3, c8 = lane & 7;
    const int sw = l16 & 7;
    const int srcoff = (c8 ^ r8) * 8;
    for (int k0 = 0; k0 < 1024; k0 += 64) {
      __syncthreads();
#pragma unroll
      for (int it = 0; it < 4; ++it) {
        const int row = wave * 32 + it * 8 + r8;
        async_ld16(A + (size_t)(m0 + row) * 2048 + k0 + srcoff, As + row * 64 + c8 * 8);
        async_ld16(B + (size_t)(n0 + row) * 2048 + k0 + srcoff, Bs + row * 64 + c8 * 8);
      }
      __syncthreads();
#pragma unroll
      for (int ks = 0; ks < 64; ks += 32) {
        bf16x8 af[4], bg[4];
#pragma unroll
        for (int mi = 0; mi < 4; ++mi)
          af[mi] = *(const bf16x8*)&As[(wm + mi * 16 + l16) * 64 + ((((ks >> 3) + quad) ^ sw) << 3)];
#pragma unroll
        for (int ni = 0; ni < 4; ++ni)
          bg[ni] = *(const bf16x8*)&Bs[(wn + ni * 16 + l16) * 64 + ((((ks >> 3) + quad) ^ sw) << 3)];
#pragma unroll
        for (int mi = 0; mi < 4; ++mi)
#pragma unroll
          for (int ni = 0; ni < 4; ++ni)
            acc[mi][ni] = __builtin_amdgcn_mfma_f32_16x16x32_bf16(af[mi], bg[ni], acc[mi][ni], 0, 0, 0);
      }
    }
  } else {
    // ---------------- K/V path: fused 3-term, BK=32, 4 tiles ----------------
    bf16* Ah = (bf16*)smem;          // 128*32 each (8KB)
    bf16* Al = Ah + 128 * 32;
    bf16* Bh = Al + 128 * 32;
    bf16* Bl = Bh + 128 * 32;
    const int rr0 = tid >> 2;        // 0..63
    const int sl = tid & 3;          // 16B slot within 64B row
    const int rsw = quad ^ ((l16 >> 1) & 3);  // read-side swizzled slot (bank-spread)
    for (int k0 = 0; k0 < 1024; k0 += 32) {
      __syncthreads();
#pragma unroll
      for (int rr = 0; rr < 2; ++rr) {
        const int row = rr * 64 + rr0;
        const int soff = ((sl ^ ((row >> 1) & 3)) << 3);  // swizzled source elem offset
        const bf16* arow = A + (size_t)(m0 + row) * 2048 + k0 + soff;
        const bf16* brow = B + (size_t)(n0 + row) * 2048 + k0 + soff;
        async_ld16(arow,        Ah + row * 32 + sl * 8);
        async_ld16(arow + 1024, Al + row * 32 + sl * 8);
        async_ld16(brow,        Bh + row * 32 + sl * 8);
        async_ld16(brow + 1024, Bl + row * 32 + sl * 8);
      }
      __syncthreads();
#pragma unroll
      for (int cb = 0; cb < 3; ++cb) {
        const bf16* Asrc = (cb == 1) ? Al : Ah;
        const bf16* Bsrc = (cb == 2) ? Bl : Bh;
        bf16x8 af[4], bg[4];
#pragma unroll
        for (int mi = 0; mi < 4; ++mi)
          af[mi] = *(const bf16x8*)&Asrc[(wm + mi * 16 + l16) * 32 + (rsw << 3)];
#pragma unroll
        for (int ni = 0; ni < 4; ++ni)
          bg[ni] = *(const bf16x8*)&Bsrc[(wn + ni * 16 + l16) * 32 + (rsw << 3)];
#pragma unroll
        for (int mi = 0; mi < 4; ++mi)
#pragma unroll
          for (int ni = 0; ni < 4; ++ni)
            acc[mi][ni] = __builtin_amdgcn_mfma_f32_16x16x32_bf16(af[mi], bg[ni], acc[mi][ni], 0, 0, 0);
      }
    }
  }

  bf16* Ct = (bf16*)smem;  // epilogue alias
  __syncthreads();  // K-loop LDS reads done; safe to overwrite with C-tile
#pragma unroll
  for (int mi = 0; mi < 4; ++mi) {
    const int ml = wm + mi * 16 + quad * 4;
#pragma unroll
    for (int ni = 0; ni < 4; ++ni) {
      const int nl = wn + ni * 16 + l16;
#pragma unroll
      for (int r = 0; r < 4; ++r) {
        const float v = acc[mi][ni][r];
        bf16 o;
        if (region == 0) o = (bf16)(v * SCALE);
        else             o = (bf16)((v >= 0.f) ? 1.f : -1.f);
        Ct[(ml + r) * CT + nl] = o;
      }
    }
  }
  __syncthreads();
  // coalesced store: thread -> (row = tid>>1, half = tid&1) = 64 contiguous bf16
  {
    const int row = tid >> 1, half = tid & 1;
    const int nn = (n0 & 1023) + half * 64;
    const int h = nn >> 6;
    const int b = m0 >> 12, t = (m0 & 4095) + row;
    bf16* base = (region == 0) ? Qws : (region == 1) ? Kws : Vws;
    bf16* dst = base + ((size_t)(b * 16 + h) * 4096 + t) * 64;
    const bf16* src = &Ct[row * CT + half * 64];
#pragma unroll
    for (int u = 0; u < 8; ++u)
      *(bf16x8*)(dst + u * 8) = *(const bf16x8*)(src + u * 8);
  }
}

// ---------------------------------------------------------------------------
// Pass 2: per-chunk KV outer product via MFMA: ckv[i][dd] = sum_t K[t,i]*V[t,dd]
// K,V are exact +-1 bf16; products/sums exact in fp32 (ints <= 64) -> bit-exact.
// ---------------------------------------------------------------------------
__global__ __launch_bounds__(256) void k_ckv(
    const bf16* __restrict__ Kws, const bf16* __restrict__ Vws, float* __restrict__ ckv)
{
  __shared__ bf16 Kt[64 * AP];  // [i][t]
  __shared__ bf16 Vt[64 * AP];  // [dd][t]
  const int tid = threadIdx.x;
  const int nchunk = blockIdx.x & 63, bh = blockIdx.x >> 6;
  const size_t tbase = ((size_t)bh * 4096 + (size_t)nchunk * 64) * 64;
  const int row = tid >> 2, c0 = (tid & 3) << 4;
  {
    const bf16x8* gk = (const bf16x8*)(Kws + tbase + row * 64 + c0);
    const bf16x8* gv = (const bf16x8*)(Vws + tbase + row * 64 + c0);
    bf16x8 k0 = gk[0], k1 = gk[1], v0 = gv[0], v1 = gv[1];
#pragma unroll
    for (int u = 0; u < 8; ++u) {
      Kt[(c0 + u) * AP + row] = k0[u];
      Kt[(c0 + 8 + u) * AP + row] = k1[u];
      Vt[(c0 + u) * AP + row] = v0[u];
      Vt[(c0 + 8 + u) * AP + row] = v1[u];
    }
  }
  __syncthreads();
  const int wave = tid >> 6, lane = tid & 63;
  const int quad = lane >> 4, l16 = lane & 15;
  const int ti = wave;
  bf16x8 ka[2];
#pragma unroll
  for (int kk = 0; kk < 2; ++kk)
    ka[kk] = *(const bf16x8*)&Kt[(ti * 16 + l16) * AP + kk * 32 + quad * 8];
  float* dst = ckv + ((size_t)bh * 64 + nchunk) * 4096;
#pragma unroll
  for (int td = 0; td < 4; ++td) {
    f32x4 acc = {};
#pragma unroll
    for (int kk = 0; kk < 2; ++kk) {
      const bf16x8 vb = *(const bf16x8*)&Vt[(td * 16 + l16) * AP + kk * 32 + quad * 8];
      acc = __builtin_amdgcn_mfma_f32_16x16x32_bf16(ka[kk], vb, acc, 0, 0, 0);
    }
#pragma unroll
    for (int r = 0; r < 4; ++r)
      dst[(ti * 16 + quad * 4 + r) * 64 + td * 16 + l16] = acc[r];
  }
}

// ---------------------------------------------------------------------------
// Pass 3: in-place exclusive prefix scan over chunks + final_state.
// ---------------------------------------------------------------------------
__global__ __launch_bounds__(256) void k_scan(float* __restrict__ ckv, float* __restrict__ fin)
{
  const int idx = blockIdx.x * 256 + threadIdx.x;
  float* p = ckv + ((size_t)(idx >> 12)) * 64 * 4096 + (idx & 4095);
  float run = 0.f;
#pragma unroll
  for (int n = 0; n < 64; ++n) {
    const float v = p[(size_t)n * 4096];
    p[(size_t)n * 4096] = run;
    run += v;
  }
  fin[idx] = run;
}

// ---------------------------------------------------------------------------
// Pass 4: per-chunk attention via MFMA: O = (Q K^T . mask) V + Q (Phi + Plo)
// LDS slimmed to 5 arrays (46KB -> 3 blocks/CU): Ss and the f16 O-tile alias
// Qs (qa is register-resident after the extra barrier).
// ---------------------------------------------------------------------------
__global__ __launch_bounds__(256) void k_attn(
    const bf16* __restrict__ Qws, const bf16* __restrict__ Kws, const bf16* __restrict__ Vws,
    const float* __restrict__ pref, f16* __restrict__ attn)
{
  __shared__ bf16 Qs[64 * AP];  // staged Q -> scores Ss -> f16 O-tile
  __shared__ bf16 Ks[64 * AP];  // [t][d]
  __shared__ bf16 Vt[64 * AP];  // [dd][t]   (transposed)
  __shared__ bf16 Ph[64 * AP];  // [dd][k]   (transposed, hi)
  __shared__ bf16 Pl[64 * AP];  // [dd][k]   (transposed, lo)
  const int tid = threadIdx.x;
  const int blk = blockIdx.x;
  const int nchunk = blk & 63, bh = blk >> 6;
  const int b = bh >> 4, h = bh & 15;
  const size_t tbase = ((size_t)bh * 4096 + (size_t)nchunk * 64) * 64;
  const int row = tid >> 2, c0 = (tid & 3) << 4;
  {
    const bf16x8* gq = (const bf16x8*)(Qws + tbase + row * 64 + c0);
    *(bf16x8*)&Qs[row * AP + c0] = gq[0];
    *(bf16x8*)&Qs[row * AP + c0 + 8] = gq[1];
    const bf16x8* gk = (const bf16x8*)(Kws + tbase + row * 64 + c0);
    *(bf16x8*)&Ks[row * AP + c0] = gk[0];
    *(bf16x8*)&Ks[row * AP + c0 + 8] = gk[1];
    const bf16x8* gv = (const bf16x8*)(Vws + tbase + row * 64 + c0);
    bf16x8 v0 = gv[0], v1 = gv[1];
#pragma unroll
    for (int u = 0; u < 8; ++u) {
      Vt[(c0 + u) * AP + row] = v0[u];
      Vt[(c0 + 8 + u) * AP + row] = v1[u];
    }
    const float* gp = pref + ((size_t)bh * 64 + nchunk) * 4096 + row * 64 + c0;
#pragma unroll
    for (int u = 0; u < 16; ++u) {
      const float p = gp[u];
      const bf16 hi = (bf16)p;
      Ph[(c0 + u) * AP + row] = hi;
      Pl[(c0 + u) * AP + row] = (bf16)(p - (float)hi);
    }
  }
  __syncthreads();

  const int wave = tid >> 6, lane = tid & 63;
  const int quad = lane >> 4, l16 = lane & 15;
  const int ti = wave;

  bf16x8 qa[2];
#pragma unroll
  for (int kk = 0; kk < 2; ++kk)
    qa[kk] = *(const bf16x8*)&Qs[(ti * 16 + l16) * AP + kk * 32 + quad * 8];
  __syncthreads();  // all waves hold qa in regs; Qs space reusable as Ss

  bf16* Ss = Qs;

  // S = Q K^T  (i-strip ti x all 4 j-tiles)
  f32x4 sacc[4] = {};
#pragma unroll
  for (int tj = 0; tj < 4; ++tj)
#pragma unroll
    for (int kk = 0; kk < 2; ++kk) {
      const bf16x8 kb = *(const bf16x8*)&Ks[(tj * 16 + l16) * AP + kk * 32 + quad * 8];
      sacc[tj] = __builtin_amdgcn_mfma_f32_16x16x32_bf16(qa[kk], kb, sacc[tj], 0, 0, 0);
    }
  // mask + write S (C-layout: row = quad*4+r, col = l16)
#pragma unroll
  for (int tj = 0; tj < 4; ++tj)
#pragma unroll
    for (int r = 0; r < 4; ++r) {
      const int i = ti * 16 + quad * 4 + r;
      const int jj = tj * 16 + l16;
      Ss[i * AP + jj] = (bf16)((jj <= i) ? sacc[tj][r] : 0.f);
    }
  __syncthreads();

  // O = S V + Q Phi + Q Plo   (i-strip ti x 4 dd-tiles)
  bf16x8 sa[2];
#pragma unroll
  for (int kk = 0; kk < 2; ++kk)
    sa[kk] = *(const bf16x8*)&Ss[(ti * 16 + l16) * AP + kk * 32 + quad * 8];
  f32x4 oacc[4] = {};
#pragma unroll
  for (int td = 0; td < 4; ++td) {
#pragma unroll
    for (int kk = 0; kk < 2; ++kk) {
      const bf16x8 vb = *(const bf16x8*)&Vt[(td * 16 + l16) * AP + kk * 32 + quad * 8];
      oacc[td] = __builtin_amdgcn_mfma_f32_16x16x32_bf16(sa[kk], vb, oacc[td], 0, 0, 0);
    }
#pragma unroll
    for (int kk = 0; kk < 2; ++kk) {
      const bf16x8 pb = *(const bf16x8*)&Ph[(td * 16 + l16) * AP + kk * 32 + quad * 8];
      oacc[td] = __builtin_amdgcn_mfma_f32_16x16x32_bf16(qa[kk], pb, oacc[td], 0, 0, 0);
      const bf16x8 pb2 = *(const bf16x8*)&Pl[(td * 16 + l16) * AP + kk * 32 + quad * 8];
      oacc[td] = __builtin_amdgcn_mfma_f32_16x16x32_bf16(qa[kk], pb2, oacc[td], 0, 0, 0);
    }
  }
  __syncthreads();  // all MFMA reads of Ss done; reuse as f16 O-tile
  f16* Os = (f16*)Ss;
#pragma unroll
  for (int td = 0; td < 4; ++td)
#pragma unroll
    for (int r = 0; r < 4; ++r) {
      const int i = ti * 16 + quad * 4 + r;
      const int dd = td * 16 + l16;
      Os[i * AP + dd] = (f16)oacc[td][r];
    }
  __syncthreads();
  // coalesced store: thread -> (row i2 = tid>>2, quarter q4 = tid&3) = 32B
  {
    const int i2 = tid >> 2, q4 = tid & 3;
    const int t = nchunk * 64 + i2;
    f16* dst = attn + ((size_t)(b * 4096 + t)) * 1024 + h * 64 + q4 * 16;
    const f16* src = &Os[i2 * AP + q4 * 16];
    *(f16x8*)(dst) = *(const f16x8*)(src);
    *(f16x8*)(dst + 8) = *(const f16x8*)(src + 8);
  }
}

// ---------------------------------------------------------------------------
// Pass 5: output projection GEMM (f16): out[m][n] = sum_k attn[m][k]*wo[n][k]
// Retiled 128x64 (M x N), grid (16,64) = 1024 blocks, 24KB LDS -> better
// occupancy for this small-K latency-bound GEMM.
// ---------------------------------------------------------------------------
__global__ __launch_bounds__(256) void k_gemm_out(
    const f16* __restrict__ A, const f16* __restrict__ B, float* __restrict__ out)
{
  __shared__ f16 As[128 * 64];  // 16KB
  __shared__ f16 Bs[64 * 64];   // 8KB
  const int tid = threadIdx.x;
  const int wave = tid >> 6, lane = tid & 63;
  const int quad = lane >> 4, l16 = lane & 15;
  const int n0 = blockIdx.x * 64;
  const int m0 = blockIdx.y * 128;
  const int wm = (wave >> 1) << 6, wn = (wave & 1) << 5;  // wave-tile 64x32
  const int r8 = lane >> 3, c8 = lane & 7;
  const int sw = l16 & 7;
  const int srcoff = (c8 ^ r8) * 8;
  f32x4 acc[4][2] = {};

  for (int k0 = 0; k0 < 1024; k0 += 64) {
    __syncthreads();
#pragma unroll
    for (int it = 0; it < 4; ++it) {
      const int row = wave * 32 + it * 8 + r8;
      async_ld16(A + (size_t)(m0 + row) * 1024 + k0 + srcoff, As + row * 64 + c8 * 8);
    }
#pragma unroll
    for (int it = 0; it < 2; ++it) {
      const int row = wave * 16 + it * 8 + r8;
      async_ld16(B + (size_t)(n0 + row) * 1024 + k0 + srcoff, Bs + row * 64 + c8 * 8);
    }
    __syncthreads();
#pragma unroll
    for (int ks = 0; ks < 64; ks += 32) {
      f16x8 af[4], bg[2];
#pragma unroll
      for (int mi = 0; mi < 4; ++mi)
        af[mi] = *(const f16x8*)&As[(wm + mi * 16 + l16) * 64 + ((((ks >> 3) + quad) ^ sw) << 3)];
#pragma unroll
      for (int ni = 0; ni < 2; ++ni)
        bg[ni] = *(const f16x8*)&Bs[(wn + ni * 16 + l16) * 64 + ((((ks >> 3) + quad) ^ sw) << 3)];
#pragma unroll
      for (int mi = 0; mi < 4; ++mi)
#pragma unroll
        for (int ni = 0; ni < 2; ++ni)
          acc[mi][ni] = __builtin_amdgcn_mfma_f32_16x16x32_f16(af[mi], bg[ni], acc[mi][ni], 0, 0, 0);
    }
  }
#pragma unroll
  for (int mi = 0; mi < 4; ++mi)
#pragma unroll
    for (int ni = 0; ni < 2; ++ni)
#pragma unroll
      for (int r = 0; r < 4; ++r) {
        const int m = m0 + wm + mi * 16 + quad * 4 + r;
        const int n = n0 + wn + ni * 16 + l16;
        out[(size_t)m * 1024 + n] = acc[mi][ni][r];
      }
}

// ---------------------------------------------------------------------------
extern "C" void kernel_launch(void* const* d_in, const int* in_sizes, int n_in,
                              void* d_out, int out_size, void* d_ws, size_t ws_size,
                              hipStream_t stream)
{
  const float* x = (const float*)d_in[0];
  const float* wqkv = (const float*)d_in[1];
  const float* wo = (const float*)d_in[2];
  float* out = (float*)d_out;
  char* ws = (char*)d_ws;

  bf16* xsplit = (bf16*)(ws);
  bf16* wsplit = (bf16*)(ws + 33554432);
  f16*  wo16   = (f16*)(ws + 46137344);
  bf16* Qws    = (bf16*)(ws + 48234496);
  bf16* Kws    = (bf16*)(ws + 65011712);
  bf16* Vws    = (bf16*)(ws + 81788928);
  float* ckv   = (float*)(ws + 98566144);
  f16*  attn   = (f16*)(ws + 132120576);
  float* fin   = out + 8388608;

  k_convert<<<12288, 256, 0, stream>>>(x, wqkv, wo, xsplit, wsplit, wo16);
  k_gemm_qkv<<<dim3(24, 64), 256, 0, stream>>>(xsplit, wsplit, Qws, Kws, Vws);
  k_ckv<<<2048, 256, 0, stream>>>(Kws, Vws, ckv);
  k_scan<<<512, 256, 0, stream>>>(ckv, fin);
  k_attn<<<2048, 256, 0, stream>>>(Qws, Kws, Vws, ckv, attn);
  k_gemm_out<<<dim3(16, 64), 256, 0, stream>>>(attn, wo16, out);
}

// Round 8
// 283.875 us; speedup vs baseline: 1.0766x; 1.0766x over previous
//
#include <hip/hip_runtime.h>

typedef __bf16 bf16;
typedef __bf16 bf16x8 __attribute__((ext_vector_type(8)));
typedef _Float16 f16;
typedef _Float16 f16x8 __attribute__((ext_vector_type(8)));
typedef float f32x4 __attribute__((ext_vector_type(4)));
typedef short s16x8 __attribute__((ext_vector_type(8)));

#define SCALE 0.125f
#define AP 72   // bf16 LDS row stride for attn/ckv tiles (64 + 8 pad)
#define CT 128  // bf16 LDS row stride for 128-wide C-tile (aliases As|Bs exactly, 32KB)

// ---------------------------------------------------------------------------
// async global->LDS, 16B per lane (wave-uniform LDS base + lane*16 layout)
// ---------------------------------------------------------------------------
__device__ __forceinline__ void async_ld16(const void* g, void* l) {
  __builtin_amdgcn_global_load_lds((const __attribute__((address_space(1))) void*)g,
                                   (__attribute__((address_space(3))) void*)l, 16, 0, 0);
}

// ---------------------------------------------------------------------------
// Pass 0: convert/split inputs (float4-vectorized).
// ---------------------------------------------------------------------------
__global__ __launch_bounds__(256) void k_convert(
    const float* __restrict__ x, const float* __restrict__ wqkv, const float* __restrict__ wo,
    bf16* __restrict__ xsplit, bf16* __restrict__ wsplit, f16* __restrict__ wo16)
{
  const int N1 = 2097152, N2 = 786432, N3 = 262144;  // in float4 units
  const int i = blockIdx.x * 256 + threadIdx.x;
  if (i < N1) {
    f32x4 v = ((const f32x4*)x)[i];
    int e = i * 4, m = e >> 10, c = e & 1023;
    bf16 hi[4], lo[4];
#pragma unroll
    for (int u = 0; u < 4; ++u) { hi[u] = (bf16)v[u]; lo[u] = (bf16)(v[u] - (float)hi[u]); }
    *(ulong1*)&xsplit[(size_t)m * 2048 + c] = *(ulong1*)hi;
    *(ulong1*)&xsplit[(size_t)m * 2048 + 1024 + c] = *(ulong1*)lo;
  } else if (i < N1 + N2) {
    int j = i - N1;
    f32x4 v = ((const f32x4*)wqkv)[j];
    int e = j * 4, n = e >> 10, c = e & 1023;
    bf16 hi[4], lo[4];
#pragma unroll
    for (int u = 0; u < 4; ++u) { hi[u] = (bf16)v[u]; lo[u] = (bf16)(v[u] - (float)hi[u]); }
    *(ulong1*)&wsplit[(size_t)n * 2048 + c] = *(ulong1*)hi;
    *(ulong1*)&wsplit[(size_t)n * 2048 + 1024 + c] = *(ulong1*)lo;
  } else if (i < N1 + N2 + N3) {
    int j = i - N1 - N2;
    f32x4 v = ((const f32x4*)wo)[j];
    f16 h[4];
#pragma unroll
    for (int u = 0; u < 4; ++u) h[u] = (f16)v[u];
    *(ulong1*)&wo16[(size_t)j * 4] = *(ulong1*)h;
  }
}

// ---------------------------------------------------------------------------
// Pass 1: QKV GEMM (R7-proven: fused 3-term K/V path, conflict-free swizzle).
// ---------------------------------------------------------------------------
__global__ __launch_bounds__(256) void k_gemm_qkv(
    const bf16* __restrict__ A, const bf16* __restrict__ B,
    bf16* __restrict__ Qws, bf16* __restrict__ Kws, bf16* __restrict__ Vws)
{
  __shared__ char smem[32768];
  const int tid = threadIdx.x;
  const int wave = tid >> 6, lane = tid & 63;
  const int quad = lane >> 4, l16 = lane & 15;
  const int bxr = (blockIdx.x < 16) ? (blockIdx.x + 8) : (blockIdx.x - 16);
  const int n0 = bxr * 128;
  const int m0 = blockIdx.y * 128;
  const int wm = (wave >> 1) << 6, wn = (wave & 1) << 6;
  const int region = n0 >> 10;  // 0=q, 1=k, 2=v
  f32x4 acc[4][4] = {};

  if (region == 0) {
    bf16* As = (bf16*)smem;
    bf16* Bs = As + 128 * 64;
    const int r8 = lane >> 3, c8 = lane & 7;
    const int sw = l16 & 7;
    const int srcoff = (c8 ^ r8) * 8;
    for (int k0 = 0; k0 < 1024; k0 += 64) {
      __syncthreads();
#pragma unroll
      for (int it = 0; it < 4; ++it) {
        const int row = wave * 32 + it * 8 + r8;
        async_ld16(A + (size_t)(m0 + row) * 2048 + k0 + srcoff, As + row * 64 + c8 * 8);
        async_ld16(B + (size_t)(n0 + row) * 2048 + k0 + srcoff, Bs + row * 64 + c8 * 8);
      }
      __syncthreads();
#pragma unroll
      for (int ks = 0; ks < 64; ks += 32) {
        bf16x8 af[4], bg[4];
#pragma unroll
        for (int mi = 0; mi < 4; ++mi)
          af[mi] = *(const bf16x8*)&As[(wm + mi * 16 + l16) * 64 + ((((ks >> 3) + quad) ^ sw) << 3)];
#pragma unroll
        for (int ni = 0; ni < 4; ++ni)
          bg[ni] = *(const bf16x8*)&Bs[(wn + ni * 16 + l16) * 64 + ((((ks >> 3) + quad) ^ sw) << 3)];
#pragma unroll
        for (int mi = 0; mi < 4; ++mi)
#pragma unroll
          for (int ni = 0; ni < 4; ++ni)
            acc[mi][ni] = __builtin_amdgcn_mfma_f32_16x16x32_bf16(af[mi], bg[ni], acc[mi][ni], 0, 0, 0);
      }
    }
  } else {
    bf16* Ah = (bf16*)smem;
    bf16* Al = Ah + 128 * 32;
    bf16* Bh = Al + 128 * 32;
    bf16* Bl = Bh + 128 * 32;
    const int rr0 = tid >> 2;
    const int sl = tid & 3;
    const int rsw = quad ^ ((l16 >> 1) & 3);
    for (int k0 = 0; k0 < 1024; k0 += 32) {
      __syncthreads();
#pragma unroll
      for (int rr = 0; rr < 2; ++rr) {
        const int row = rr * 64 + rr0;
        const int soff = ((sl ^ ((row >> 1) & 3)) << 3);
        const bf16* arow = A + (size_t)(m0 + row) * 2048 + k0 + soff;
        const bf16* brow = B + (size_t)(n0 + row) * 2048 + k0 + soff;
        async_ld16(arow,        Ah + row * 32 + sl * 8);
        async_ld16(arow + 1024, Al + row * 32 + sl * 8);
        async_ld16(brow,        Bh + row * 32 + sl * 8);
        async_ld16(brow + 1024, Bl + row * 32 + sl * 8);
      }
      __syncthreads();
#pragma unroll
      for (int cb = 0; cb < 3; ++cb) {
        const bf16* Asrc = (cb == 1) ? Al : Ah;
        const bf16* Bsrc = (cb == 2) ? Bl : Bh;
        bf16x8 af[4], bg[4];
#pragma unroll
        for (int mi = 0; mi < 4; ++mi)
          af[mi] = *(const bf16x8*)&Asrc[(wm + mi * 16 + l16) * 32 + (rsw << 3)];
#pragma unroll
        for (int ni = 0; ni < 4; ++ni)
          bg[ni] = *(const bf16x8*)&Bsrc[(wn + ni * 16 + l16) * 32 + (rsw << 3)];
#pragma unroll
        for (int mi = 0; mi < 4; ++mi)
#pragma unroll
          for (int ni = 0; ni < 4; ++ni)
            acc[mi][ni] = __builtin_amdgcn_mfma_f32_16x16x32_bf16(af[mi], bg[ni], acc[mi][ni], 0, 0, 0);
      }
    }
  }

  bf16* Ct = (bf16*)smem;
  __syncthreads();
#pragma unroll
  for (int mi = 0; mi < 4; ++mi) {
    const int ml = wm + mi * 16 + quad * 4;
#pragma unroll
    for (int ni = 0; ni < 4; ++ni) {
      const int nl = wn + ni * 16 + l16;
#pragma unroll
      for (int r = 0; r < 4; ++r) {
        const float v = acc[mi][ni][r];
        bf16 o;
        if (region == 0) o = (bf16)(v * SCALE);
        else             o = (bf16)((v >= 0.f) ? 1.f : -1.f);
        Ct[(ml + r) * CT + nl] = o;
      }
    }
  }
  __syncthreads();
  {
    const int row = tid >> 1, half = tid & 1;
    const int nn = (n0 & 1023) + half * 64;
    const int h = nn >> 6;
    const int b = m0 >> 12, t = (m0 & 4095) + row;
    bf16* base = (region == 0) ? Qws : (region == 1) ? Kws : Vws;
    bf16* dst = base + ((size_t)(b * 16 + h) * 4096 + t) * 64;
    const bf16* src = &Ct[row * CT + half * 64];
#pragma unroll
    for (int u = 0; u < 8; ++u)
      *(bf16x8*)(dst + u * 8) = *(const bf16x8*)(src + u * 8);
  }
}

// ---------------------------------------------------------------------------
// Pass 2: per-chunk KV outer product via MFMA -> int16 (exact ints |v|<=64).
// ---------------------------------------------------------------------------
__global__ __launch_bounds__(256) void k_ckv(
    const bf16* __restrict__ Kws, const bf16* __restrict__ Vws, short* __restrict__ ckv)
{
  __shared__ bf16 Kt[64 * AP];  // [i][t]
  __shared__ bf16 Vt[64 * AP];  // [dd][t]
  const int tid = threadIdx.x;
  const int nchunk = blockIdx.x & 63, bh = blockIdx.x >> 6;
  const size_t tbase = ((size_t)bh * 4096 + (size_t)nchunk * 64) * 64;
  const int row = tid >> 2, c0 = (tid & 3) << 4;
  {
    const bf16x8* gk = (const bf16x8*)(Kws + tbase + row * 64 + c0);
    const bf16x8* gv = (const bf16x8*)(Vws + tbase + row * 64 + c0);
    bf16x8 k0 = gk[0], k1 = gk[1], v0 = gv[0], v1 = gv[1];
#pragma unroll
    for (int u = 0; u < 8; ++u) {
      Kt[(c0 + u) * AP + row] = k0[u];
      Kt[(c0 + 8 + u) * AP + row] = k1[u];
      Vt[(c0 + u) * AP + row] = v0[u];
      Vt[(c0 + 8 + u) * AP + row] = v1[u];
    }
  }
  __syncthreads();
  const int wave = tid >> 6, lane = tid & 63;
  const int quad = lane >> 4, l16 = lane & 15;
  const int ti = wave;
  bf16x8 ka[2];
#pragma unroll
  for (int kk = 0; kk < 2; ++kk)
    ka[kk] = *(const bf16x8*)&Kt[(ti * 16 + l16) * AP + kk * 32 + quad * 8];
  short* dst = ckv + ((size_t)bh * 64 + nchunk) * 4096;
#pragma unroll
  for (int td = 0; td < 4; ++td) {
    f32x4 acc = {};
#pragma unroll
    for (int kk = 0; kk < 2; ++kk) {
      const bf16x8 vb = *(const bf16x8*)&Vt[(td * 16 + l16) * AP + kk * 32 + quad * 8];
      acc = __builtin_amdgcn_mfma_f32_16x16x32_bf16(ka[kk], vb, acc, 0, 0, 0);
    }
#pragma unroll
    for (int r = 0; r < 4; ++r)
      dst[(ti * 16 + quad * 4 + r) * 64 + td * 16 + l16] = (short)acc[r];
  }
}

// ---------------------------------------------------------------------------
// Pass 3: in-place exclusive prefix scan over chunks (int16) + final_state.
// ---------------------------------------------------------------------------
__global__ __launch_bounds__(256) void k_scan(short* __restrict__ ckv, float* __restrict__ fin)
{
  const int idx = blockIdx.x * 256 + threadIdx.x;
  short* p = ckv + ((size_t)(idx >> 12)) * 64 * 4096 + (idx & 4095);
  int run = 0;
#pragma unroll
  for (int n = 0; n < 64; ++n) {
    const int v = p[(size_t)n * 4096];
    p[(size_t)n * 4096] = (short)run;  // exclusive prefix, |v| <= 4032
    run += v;
  }
  fin[idx] = (float)run;
}

// ---------------------------------------------------------------------------
// Pass 4: per-chunk attention via MFMA: O = (Q K^T . mask) V + Q (Phi + Plo)
// Prefix read as int16; bf16 hi/lo split exact (residual <= 16, small int).
// Ss and the f16 O-tile alias Qs (46KB LDS -> 3 blocks/CU).
// ---------------------------------------------------------------------------
__global__ __launch_bounds__(256) void k_attn(
    const bf16* __restrict__ Qws, const bf16* __restrict__ Kws, const bf16* __restrict__ Vws,
    const short* __restrict__ pref, f16* __restrict__ attn)
{
  __shared__ bf16 Qs[64 * AP];  // staged Q -> scores Ss -> f16 O-tile
  __shared__ bf16 Ks[64 * AP];  // [t][d]
  __shared__ bf16 Vt[64 * AP];  // [dd][t]
  __shared__ bf16 Ph[64 * AP];  // [dd][k] hi
  __shared__ bf16 Pl[64 * AP];  // [dd][k] lo
  const int tid = threadIdx.x;
  const int blk = blockIdx.x;
  const int nchunk = blk & 63, bh = blk >> 6;
  const int b = bh >> 4, h = bh & 15;
  const size_t tbase = ((size_t)bh * 4096 + (size_t)nchunk * 64) * 64;
  const int row = tid >> 2, c0 = (tid & 3) << 4;
  {
    const bf16x8* gq = (const bf16x8*)(Qws + tbase + row * 64 + c0);
    *(bf16x8*)&Qs[row * AP + c0] = gq[0];
    *(bf16x8*)&Qs[row * AP + c0 + 8] = gq[1];
    const bf16x8* gk = (const bf16x8*)(Kws + tbase + row * 64 + c0);
    *(bf16x8*)&Ks[row * AP + c0] = gk[0];
    *(bf16x8*)&Ks[row * AP + c0 + 8] = gk[1];
    const bf16x8* gv = (const bf16x8*)(Vws + tbase + row * 64 + c0);
    bf16x8 v0 = gv[0], v1 = gv[1];
#pragma unroll
    for (int u = 0; u < 8; ++u) {
      Vt[(c0 + u) * AP + row] = v0[u];
      Vt[(c0 + 8 + u) * AP + row] = v1[u];
    }
    const short* gp = pref + ((size_t)bh * 64 + nchunk) * 4096 + row * 64 + c0;
    s16x8 p0 = *(const s16x8*)(gp);
    s16x8 p1 = *(const s16x8*)(gp + 8);
#pragma unroll
    for (int u = 0; u < 8; ++u) {
      {
        const float p = (float)p0[u];
        const bf16 hi = (bf16)p;
        Ph[(c0 + u) * AP + row] = hi;
        Pl[(c0 + u) * AP + row] = (bf16)(p - (float)hi);
      }
      {
        const float p = (float)p1[u];
        const bf16 hi = (bf16)p;
        Ph[(c0 + 8 + u) * AP + row] = hi;
        Pl[(c0 + 8 + u) * AP + row] = (bf16)(p - (float)hi);
      }
    }
  }
  __syncthreads();

  const int wave = tid >> 6, lane = tid & 63;
  const int quad = lane >> 4, l16 = lane & 15;
  const int ti = wave;

  bf16x8 qa[2];
#pragma unroll
  for (int kk = 0; kk < 2; ++kk)
    qa[kk] = *(const bf16x8*)&Qs[(ti * 16 + l16) * AP + kk * 32 + quad * 8];
  __syncthreads();  // qa in regs; Qs reusable as Ss

  bf16* Ss = Qs;

  // S = Q K^T
  f32x4 sacc[4] = {};
#pragma unroll
  for (int tj = 0; tj < 4; ++tj)
#pragma unroll
    for (int kk = 0; kk < 2; ++kk) {
      const bf16x8 kb = *(const bf16x8*)&Ks[(tj * 16 + l16) * AP + kk * 32 + quad * 8];
      sacc[tj] = __builtin_amdgcn_mfma_f32_16x16x32_bf16(qa[kk], kb, sacc[tj], 0, 0, 0);
    }
#pragma unroll
  for (int tj = 0; tj < 4; ++tj)
#pragma unroll
    for (int r = 0; r < 4; ++r) {
      const int i = ti * 16 + quad * 4 + r;
      const int jj = tj * 16 + l16;
      Ss[i * AP + jj] = (bf16)((jj <= i) ? sacc[tj][r] : 0.f);
    }
  __syncthreads();

  // O = S V + Q Phi + Q Plo
  bf16x8 sa[2];
#pragma unroll
  for (int kk = 0; kk < 2; ++kk)
    sa[kk] = *(const bf16x8*)&Ss[(ti * 16 + l16) * AP + kk * 32 + quad * 8];
  f32x4 oacc[4] = {};
#pragma unroll
  for (int td = 0; td < 4; ++td) {
#pragma unroll
    for (int kk = 0; kk < 2; ++kk) {
      const bf16x8 vb = *(const bf16x8*)&Vt[(td * 16 + l16) * AP + kk * 32 + quad * 8];
      oacc[td] = __builtin_amdgcn_mfma_f32_16x16x32_bf16(sa[kk], vb, oacc[td], 0, 0, 0);
    }
#pragma unroll
    for (int kk = 0; kk < 2; ++kk) {
      const bf16x8 pb = *(const bf16x8*)&Ph[(td * 16 + l16) * AP + kk * 32 + quad * 8];
      oacc[td] = __builtin_amdgcn_mfma_f32_16x16x32_bf16(qa[kk], pb, oacc[td], 0, 0, 0);
      const bf16x8 pb2 = *(const bf16x8*)&Pl[(td * 16 + l16) * AP + kk * 32 + quad * 8];
      oacc[td] = __builtin_amdgcn_mfma_f32_16x16x32_bf16(qa[kk], pb2, oacc[td], 0, 0, 0);
    }
  }
  __syncthreads();
  f16* Os = (f16*)Ss;
#pragma unroll
  for (int td = 0; td < 4; ++td)
#pragma unroll
    for (int r = 0; r < 4; ++r) {
      const int i = ti * 16 + quad * 4 + r;
      const int dd = td * 16 + l16;
      Os[i * AP + dd] = (f16)oacc[td][r];
    }
  __syncthreads();
  {
    const int i2 = tid >> 2, q4 = tid & 3;
    const int t = nchunk * 64 + i2;
    f16* dst = attn + ((size_t)(b * 4096 + t)) * 1024 + h * 64 + q4 * 16;
    const f16* src = &Os[i2 * AP + q4 * 16];
    *(f16x8*)(dst) = *(const f16x8*)(src);
    *(f16x8*)(dst + 8) = *(const f16x8*)(src + 8);
  }
}

// ---------------------------------------------------------------------------
// Pass 5: output projection GEMM (f16) — R6-proven 128x128 tile, grid (8,64).
// ---------------------------------------------------------------------------
__global__ __launch_bounds__(256) void k_gemm_out(
    const f16* __restrict__ A, const f16* __restrict__ B, float* __restrict__ out)
{
  __shared__ f16 As[128 * 64];
  __shared__ f16 Bs[128 * 64];
  const int tid = threadIdx.x;
  const int wave = tid >> 6, lane = tid & 63;
  const int quad = lane >> 4, l16 = lane & 15;
  const int n0 = blockIdx.x * 128;
  const int m0 = blockIdx.y * 128;
  const int wm = (wave >> 1) << 6, wn = (wave & 1) << 6;
  const int r8 = lane >> 3, c8 = lane & 7;
  const int sw = l16 & 7;
  const int srcoff = (c8 ^ r8) * 8;
  f32x4 acc[4][4] = {};

  for (int k0 = 0; k0 < 1024; k0 += 64) {
    __syncthreads();
#pragma unroll
    for (int it = 0; it < 4; ++it) {
      const int row = wave * 32 + it * 8 + r8;
      async_ld16(A + (size_t)(m0 + row) * 1024 + k0 + srcoff, As + row * 64 + c8 * 8);
      async_ld16(B + (size_t)(n0 + row) * 1024 + k0 + srcoff, Bs + row * 64 + c8 * 8);
    }
    __syncthreads();
#pragma unroll
    for (int ks = 0; ks < 64; ks += 32) {
      f16x8 af[4], bg[4];
#pragma unroll
      for (int mi = 0; mi < 4; ++mi)
        af[mi] = *(const f16x8*)&As[(wm + mi * 16 + l16) * 64 + ((((ks >> 3) + quad) ^ sw) << 3)];
#pragma unroll
      for (int ni = 0; ni < 4; ++ni)
        bg[ni] = *(const f16x8*)&Bs[(wn + ni * 16 + l16) * 64 + ((((ks >> 3) + quad) ^ sw) << 3)];
#pragma unroll
      for (int mi = 0; mi < 4; ++mi)
#pragma unroll
        for (int ni = 0; ni < 4; ++ni)
          acc[mi][ni] = __builtin_amdgcn_mfma_f32_16x16x32_f16(af[mi], bg[ni], acc[mi][ni], 0, 0, 0);
    }
  }
#pragma unroll
  for (int mi = 0; mi < 4; ++mi)
#pragma unroll
    for (int ni = 0; ni < 4; ++ni)
#pragma unroll
      for (int r = 0; r < 4; ++r) {
        const int m = m0 + wm + mi * 16 + quad * 4 + r;
        const int n = n0 + wn + ni * 16 + l16;
        out[(size_t)m * 1024 + n] = acc[mi][ni][r];
      }
}

// ---------------------------------------------------------------------------
extern "C" void kernel_launch(void* const* d_in, const int* in_sizes, int n_in,
                              void* d_out, int out_size, void* d_ws, size_t ws_size,
                              hipStream_t stream)
{
  const float* x = (const float*)d_in[0];
  const float* wqkv = (const float*)d_in[1];
  const float* wo = (const float*)d_in[2];
  float* out = (float*)d_out;
  char* ws = (char*)d_ws;

  bf16* xsplit = (bf16*)(ws);
  bf16* wsplit = (bf16*)(ws + 33554432);
  f16*  wo16   = (f16*)(ws + 46137344);
  bf16* Qws    = (bf16*)(ws + 48234496);
  bf16* Kws    = (bf16*)(ws + 65011712);
  bf16* Vws    = (bf16*)(ws + 81788928);
  short* ckv   = (short*)(ws + 98566144);   // 16,777,216 B (int16 chunk-KV / prefix)
  f16*  attn   = (f16*)(ws + 132120576);
  float* fin   = out + 8388608;

  k_convert<<<12288, 256, 0, stream>>>(x, wqkv, wo, xsplit, wsplit, wo16);
  k_gemm_qkv<<<dim3(24, 64), 256, 0, stream>>>(xsplit, wsplit, Qws, Kws, Vws);
  k_ckv<<<2048, 256, 0, stream>>>(Kws, Vws, ckv);
  k_scan<<<512, 256, 0, stream>>>(ckv, fin);
  k_attn<<<2048, 256, 0, stream>>>(Qws, Kws, Vws, ckv, attn);
  k_gemm_out<<<dim3(8, 64), 256, 0, stream>>>(attn, wo16, out);
}

// Round 9
// 279.632 us; speedup vs baseline: 1.0930x; 1.0152x over previous
//
#include <hip/hip_runtime.h>

typedef __bf16 bf16;
typedef __bf16 bf16x8 __attribute__((ext_vector_type(8)));
typedef _Float16 f16;
typedef _Float16 f16x8 __attribute__((ext_vector_type(8)));
typedef float f32x4 __attribute__((ext_vector_type(4)));
typedef short s16x8 __attribute__((ext_vector_type(8)));

#define SCALE 0.125f
#define AP 72   // bf16 LDS row stride for attn/ckv tiles (64 + 8 pad)
#define CT 128  // bf16 LDS row stride for 128-wide C-tile (aliases As|Bs exactly, 32KB)

// ---------------------------------------------------------------------------
// async global->LDS, 16B per lane (wave-uniform LDS base + lane*16 layout)
// ---------------------------------------------------------------------------
__device__ __forceinline__ void async_ld16(const void* g, void* l) {
  __builtin_amdgcn_global_load_lds((const __attribute__((address_space(1))) void*)g,
                                   (__attribute__((address_space(3))) void*)l, 16, 0, 0);
}

// ---------------------------------------------------------------------------
// Pass 0: convert/split inputs (float4-vectorized).
// ---------------------------------------------------------------------------
__global__ __launch_bounds__(256) void k_convert(
    const float* __restrict__ x, const float* __restrict__ wqkv, const float* __restrict__ wo,
    bf16* __restrict__ xsplit, bf16* __restrict__ wsplit, f16* __restrict__ wo16)
{
  const int N1 = 2097152, N2 = 786432, N3 = 262144;  // in float4 units
  const int i = blockIdx.x * 256 + threadIdx.x;
  if (i < N1) {
    f32x4 v = ((const f32x4*)x)[i];
    int e = i * 4, m = e >> 10, c = e & 1023;
    bf16 hi[4], lo[4];
#pragma unroll
    for (int u = 0; u < 4; ++u) { hi[u] = (bf16)v[u]; lo[u] = (bf16)(v[u] - (float)hi[u]); }
    *(ulong1*)&xsplit[(size_t)m * 2048 + c] = *(ulong1*)hi;
    *(ulong1*)&xsplit[(size_t)m * 2048 + 1024 + c] = *(ulong1*)lo;
  } else if (i < N1 + N2) {
    int j = i - N1;
    f32x4 v = ((const f32x4*)wqkv)[j];
    int e = j * 4, n = e >> 10, c = e & 1023;
    bf16 hi[4], lo[4];
#pragma unroll
    for (int u = 0; u < 4; ++u) { hi[u] = (bf16)v[u]; lo[u] = (bf16)(v[u] - (float)hi[u]); }
    *(ulong1*)&wsplit[(size_t)n * 2048 + c] = *(ulong1*)hi;
    *(ulong1*)&wsplit[(size_t)n * 2048 + 1024 + c] = *(ulong1*)lo;
  } else if (i < N1 + N2 + N3) {
    int j = i - N1 - N2;
    f32x4 v = ((const f32x4*)wo)[j];
    f16 h[4];
#pragma unroll
    for (int u = 0; u < 4; ++u) h[u] = (f16)v[u];
    *(ulong1*)&wo16[(size_t)j * 4] = *(ulong1*)h;
  }
}

// ---------------------------------------------------------------------------
// Pass 1: QKV GEMM (R7-proven: fused 3-term K/V path, conflict-free swizzle).
// ---------------------------------------------------------------------------
__global__ __launch_bounds__(256) void k_gemm_qkv(
    const bf16* __restrict__ A, const bf16* __restrict__ B,
    bf16* __restrict__ Qws, bf16* __restrict__ Kws, bf16* __restrict__ Vws)
{
  __shared__ char smem[32768];
  const int tid = threadIdx.x;
  const int wave = tid >> 6, lane = tid & 63;
  const int quad = lane >> 4, l16 = lane & 15;
  const int bxr = (blockIdx.x < 16) ? (blockIdx.x + 8) : (blockIdx.x - 16);
  const int n0 = bxr * 128;
  const int m0 = blockIdx.y * 128;
  const int wm = (wave >> 1) << 6, wn = (wave & 1) << 6;
  const int region = n0 >> 10;  // 0=q, 1=k, 2=v
  f32x4 acc[4][4] = {};

  if (region == 0) {
    bf16* As = (bf16*)smem;
    bf16* Bs = As + 128 * 64;
    const int r8 = lane >> 3, c8 = lane & 7;
    const int sw = l16 & 7;
    const int srcoff = (c8 ^ r8) * 8;
    for (int k0 = 0; k0 < 1024; k0 += 64) {
      __syncthreads();
#pragma unroll
      for (int it = 0; it < 4; ++it) {
        const int row = wave * 32 + it * 8 + r8;
        async_ld16(A + (size_t)(m0 + row) * 2048 + k0 + srcoff, As + row * 64 + c8 * 8);
        async_ld16(B + (size_t)(n0 + row) * 2048 + k0 + srcoff, Bs + row * 64 + c8 * 8);
      }
      __syncthreads();
#pragma unroll
      for (int ks = 0; ks < 64; ks += 32) {
        bf16x8 af[4], bg[4];
#pragma unroll
        for (int mi = 0; mi < 4; ++mi)
          af[mi] = *(const bf16x8*)&As[(wm + mi * 16 + l16) * 64 + ((((ks >> 3) + quad) ^ sw) << 3)];
#pragma unroll
        for (int ni = 0; ni < 4; ++ni)
          bg[ni] = *(const bf16x8*)&Bs[(wn + ni * 16 + l16) * 64 + ((((ks >> 3) + quad) ^ sw) << 3)];
#pragma unroll
        for (int mi = 0; mi < 4; ++mi)
#pragma unroll
          for (int ni = 0; ni < 4; ++ni)
            acc[mi][ni] = __builtin_amdgcn_mfma_f32_16x16x32_bf16(af[mi], bg[ni], acc[mi][ni], 0, 0, 0);
      }
    }
  } else {
    bf16* Ah = (bf16*)smem;
    bf16* Al = Ah + 128 * 32;
    bf16* Bh = Al + 128 * 32;
    bf16* Bl = Bh + 128 * 32;
    const int rr0 = tid >> 2;
    const int sl = tid & 3;
    const int rsw = quad ^ ((l16 >> 1) & 3);
    for (int k0 = 0; k0 < 1024; k0 += 32) {
      __syncthreads();
#pragma unroll
      for (int rr = 0; rr < 2; ++rr) {
        const int row = rr * 64 + rr0;
        const int soff = ((sl ^ ((row >> 1) & 3)) << 3);
        const bf16* arow = A + (size_t)(m0 + row) * 2048 + k0 + soff;
        const bf16* brow = B + (size_t)(n0 + row) * 2048 + k0 + soff;
        async_ld16(arow,        Ah + row * 32 + sl * 8);
        async_ld16(arow + 1024, Al + row * 32 + sl * 8);
        async_ld16(brow,        Bh + row * 32 + sl * 8);
        async_ld16(brow + 1024, Bl + row * 32 + sl * 8);
      }
      __syncthreads();
#pragma unroll
      for (int cb = 0; cb < 3; ++cb) {
        const bf16* Asrc = (cb == 1) ? Al : Ah;
        const bf16* Bsrc = (cb == 2) ? Bl : Bh;
        bf16x8 af[4], bg[4];
#pragma unroll
        for (int mi = 0; mi < 4; ++mi)
          af[mi] = *(const bf16x8*)&Asrc[(wm + mi * 16 + l16) * 32 + (rsw << 3)];
#pragma unroll
        for (int ni = 0; ni < 4; ++ni)
          bg[ni] = *(const bf16x8*)&Bsrc[(wn + ni * 16 + l16) * 32 + (rsw << 3)];
#pragma unroll
        for (int mi = 0; mi < 4; ++mi)
#pragma unroll
          for (int ni = 0; ni < 4; ++ni)
            acc[mi][ni] = __builtin_amdgcn_mfma_f32_16x16x32_bf16(af[mi], bg[ni], acc[mi][ni], 0, 0, 0);
      }
    }
  }

  bf16* Ct = (bf16*)smem;
  __syncthreads();
#pragma unroll
  for (int mi = 0; mi < 4; ++mi) {
    const int ml = wm + mi * 16 + quad * 4;
#pragma unroll
    for (int ni = 0; ni < 4; ++ni) {
      const int nl = wn + ni * 16 + l16;
#pragma unroll
      for (int r = 0; r < 4; ++r) {
        const float v = acc[mi][ni][r];
        bf16 o;
        if (region == 0) o = (bf16)(v * SCALE);
        else             o = (bf16)((v >= 0.f) ? 1.f : -1.f);
        Ct[(ml + r) * CT + nl] = o;
      }
    }
  }
  __syncthreads();
  {
    const int row = tid >> 1, half = tid & 1;
    const int nn = (n0 & 1023) + half * 64;
    const int h = nn >> 6;
    const int b = m0 >> 12, t = (m0 & 4095) + row;
    bf16* base = (region == 0) ? Qws : (region == 1) ? Kws : Vws;
    bf16* dst = base + ((size_t)(b * 16 + h) * 4096 + t) * 64;
    const bf16* src = &Ct[row * CT + half * 64];
#pragma unroll
    for (int u = 0; u < 8; ++u)
      *(bf16x8*)(dst + u * 8) = *(const bf16x8*)(src + u * 8);
  }
}

// ---------------------------------------------------------------------------
// Pass 2: per-chunk KV outer product via MFMA -> int16 (exact ints |v|<=64).
// ---------------------------------------------------------------------------
__global__ __launch_bounds__(256) void k_ckv(
    const bf16* __restrict__ Kws, const bf16* __restrict__ Vws, short* __restrict__ ckv)
{
  __shared__ bf16 Kt[64 * AP];  // [i][t]
  __shared__ bf16 Vt[64 * AP];  // [dd][t]
  const int tid = threadIdx.x;
  const int nchunk = blockIdx.x & 63, bh = blockIdx.x >> 6;
  const size_t tbase = ((size_t)bh * 4096 + (size_t)nchunk * 64) * 64;
  const int row = tid >> 2, c0 = (tid & 3) << 4;
  {
    const bf16x8* gk = (const bf16x8*)(Kws + tbase + row * 64 + c0);
    const bf16x8* gv = (const bf16x8*)(Vws + tbase + row * 64 + c0);
    bf16x8 k0 = gk[0], k1 = gk[1], v0 = gv[0], v1 = gv[1];
#pragma unroll
    for (int u = 0; u < 8; ++u) {
      Kt[(c0 + u) * AP + row] = k0[u];
      Kt[(c0 + 8 + u) * AP + row] = k1[u];
      Vt[(c0 + u) * AP + row] = v0[u];
      Vt[(c0 + 8 + u) * AP + row] = v1[u];
    }
  }
  __syncthreads();
  const int wave = tid >> 6, lane = tid & 63;
  const int quad = lane >> 4, l16 = lane & 15;
  const int ti = wave;
  bf16x8 ka[2];
#pragma unroll
  for (int kk = 0; kk < 2; ++kk)
    ka[kk] = *(const bf16x8*)&Kt[(ti * 16 + l16) * AP + kk * 32 + quad * 8];
  short* dst = ckv + ((size_t)bh * 64 + nchunk) * 4096;
#pragma unroll
  for (int td = 0; td < 4; ++td) {
    f32x4 acc = {};
#pragma unroll
    for (int kk = 0; kk < 2; ++kk) {
      const bf16x8 vb = *(const bf16x8*)&Vt[(td * 16 + l16) * AP + kk * 32 + quad * 8];
      acc = __builtin_amdgcn_mfma_f32_16x16x32_bf16(ka[kk], vb, acc, 0, 0, 0);
    }
#pragma unroll
    for (int r = 0; r < 4; ++r)
      dst[(ti * 16 + quad * 4 + r) * 64 + td * 16 + l16] = (short)acc[r];
  }
}

// ---------------------------------------------------------------------------
// Pass 3: in-place exclusive prefix scan (int16, packed pairs) + final_state.
// Each thread owns 2 adjacent (i,dd) elements -> 4B packed loads/stores.
// ---------------------------------------------------------------------------
__global__ __launch_bounds__(256) void k_scan(short* __restrict__ ckv, float* __restrict__ fin)
{
  const int idx2 = blockIdx.x * 256 + threadIdx.x;   // 0..65535 = bh*2048 + ij2
  short* p = ckv + ((size_t)(idx2 >> 11)) * 262144 + (size_t)(idx2 & 2047) * 2;
  int r0 = 0, r1 = 0;
#pragma unroll
  for (int n = 0; n < 64; ++n) {
    unsigned int w = *(unsigned int*)(p + (size_t)n * 4096);
    const short a = (short)(w & 0xffff);
    const short bb = (short)(w >> 16);
    *(unsigned int*)(p + (size_t)n * 4096) =
        ((unsigned int)(unsigned short)(short)r0) | (((unsigned int)(unsigned short)(short)r1) << 16);
    r0 += a; r1 += bb;
  }
  float2 f; f.x = (float)r0; f.y = (float)r1;
  *(float2*)(fin + ((size_t)(idx2 >> 11)) * 4096 + (size_t)(idx2 & 2047) * 2) = f;
}

// ---------------------------------------------------------------------------
// Pass 4: per-chunk attention via MFMA: O = (Q K^T . mask) V + Q (Phi + Plo)
// Q fragments loaded directly from global (16B contiguous per lane, no LDS).
// K staged via async_ld16 into unpadded-64 XOR-swizzled LDS (R2-proven).
// V/P transposed in LDS as before. 44KB LDS -> 3 blocks/CU; 4 barriers.
// ---------------------------------------------------------------------------
__global__ __launch_bounds__(256) void k_attn(
    const bf16* __restrict__ Qws, const bf16* __restrict__ Kws, const bf16* __restrict__ Vws,
    const short* __restrict__ pref, f16* __restrict__ attn)
{
  __shared__ bf16 Ks[64 * 64];  // [t][d], swizzled, async-staged (8KB)
  __shared__ bf16 Vt[64 * AP];  // [dd][t]
  __shared__ bf16 Ph[64 * AP];  // [dd][k] hi
  __shared__ bf16 Pl[64 * AP];  // [dd][k] lo
  __shared__ bf16 Ss[64 * AP];  // scores; reused as f16 O-tile
  const int tid = threadIdx.x;
  const int nchunk = blockIdx.x & 63, bh = blockIdx.x >> 6;
  const int b = bh >> 4, h = bh & 15;
  const size_t tbase = ((size_t)bh * 4096 + (size_t)nchunk * 64) * 64;

  // K rows via async (64 rows x 128B = 512 16B-chunks; 2 per thread)
  {
    const int c8 = tid & 7, r0 = tid >> 3;  // r0: 0..31
#pragma unroll
    for (int it = 0; it < 2; ++it) {
      const int row = it * 32 + r0;
      async_ld16(Kws + tbase + row * 64 + ((c8 ^ (row & 7)) << 3), Ks + row * 64 + (c8 << 3));
    }
  }
  const int wave = tid >> 6, lane = tid & 63;
  const int quad = lane >> 4, l16 = lane & 15;
  const int ti = wave;
  // Q A-fragments direct from global (16B contiguous per lane)
  bf16x8 qa[2];
#pragma unroll
  for (int kk = 0; kk < 2; ++kk)
    qa[kk] = *(const bf16x8*)(Qws + tbase + (ti * 16 + l16) * 64 + kk * 32 + quad * 8);
  // V transpose + P hi/lo staging
  {
    const int row = tid >> 2, c0 = (tid & 3) << 4;
    const bf16x8* gv = (const bf16x8*)(Vws + tbase + row * 64 + c0);
    bf16x8 v0 = gv[0], v1 = gv[1];
#pragma unroll
    for (int u = 0; u < 8; ++u) {
      Vt[(c0 + u) * AP + row] = v0[u];
      Vt[(c0 + 8 + u) * AP + row] = v1[u];
    }
    const short* gp = pref + ((size_t)bh * 64 + nchunk) * 4096 + row * 64 + c0;
    s16x8 p0 = *(const s16x8*)(gp);
    s16x8 p1 = *(const s16x8*)(gp + 8);
#pragma unroll
    for (int u = 0; u < 8; ++u) {
      {
        const float p = (float)p0[u];
        const bf16 hi = (bf16)p;
        Ph[(c0 + u) * AP + row] = hi;
        Pl[(c0 + u) * AP + row] = (bf16)(p - (float)hi);
      }
      {
        const float p = (float)p1[u];
        const bf16 hi = (bf16)p;
        Ph[(c0 + 8 + u) * AP + row] = hi;
        Pl[(c0 + 8 + u) * AP + row] = (bf16)(p - (float)hi);
      }
    }
  }
  __syncthreads();

  const int sw = l16 & 7;
  // S = Q K^T
  f32x4 sacc[4] = {};
#pragma unroll
  for (int tj = 0; tj < 4; ++tj)
#pragma unroll
    for (int kk = 0; kk < 2; ++kk) {
      const bf16x8 kb = *(const bf16x8*)&Ks[(tj * 16 + l16) * 64 + (((kk * 4 + quad) ^ sw) << 3)];
      sacc[tj] = __builtin_amdgcn_mfma_f32_16x16x32_bf16(qa[kk], kb, sacc[tj], 0, 0, 0);
    }
#pragma unroll
  for (int tj = 0; tj < 4; ++tj)
#pragma unroll
    for (int r = 0; r < 4; ++r) {
      const int i = ti * 16 + quad * 4 + r;
      const int jj = tj * 16 + l16;
      Ss[i * AP + jj] = (bf16)((jj <= i) ? sacc[tj][r] : 0.f);
    }
  __syncthreads();

  // O = S V + Q Phi + Q Plo
  bf16x8 sa[2];
#pragma unroll
  for (int kk = 0; kk < 2; ++kk)
    sa[kk] = *(const bf16x8*)&Ss[(ti * 16 + l16) * AP + kk * 32 + quad * 8];
  f32x4 oacc[4] = {};
#pragma unroll
  for (int td = 0; td < 4; ++td) {
#pragma unroll
    for (int kk = 0; kk < 2; ++kk) {
      const bf16x8 vb = *(const bf16x8*)&Vt[(td * 16 + l16) * AP + kk * 32 + quad * 8];
      oacc[td] = __builtin_amdgcn_mfma_f32_16x16x32_bf16(sa[kk], vb, oacc[td], 0, 0, 0);
    }
#pragma unroll
    for (int kk = 0; kk < 2; ++kk) {
      const bf16x8 pb = *(const bf16x8*)&Ph[(td * 16 + l16) * AP + kk * 32 + quad * 8];
      oacc[td] = __builtin_amdgcn_mfma_f32_16x16x32_bf16(qa[kk], pb, oacc[td], 0, 0, 0);
      const bf16x8 pb2 = *(const bf16x8*)&Pl[(td * 16 + l16) * AP + kk * 32 + quad * 8];
      oacc[td] = __builtin_amdgcn_mfma_f32_16x16x32_bf16(qa[kk], pb2, oacc[td], 0, 0, 0);
    }
  }
  __syncthreads();
  f16* Os = (f16*)Ss;
#pragma unroll
  for (int td = 0; td < 4; ++td)
#pragma unroll
    for (int r = 0; r < 4; ++r) {
      const int i = ti * 16 + quad * 4 + r;
      const int dd = td * 16 + l16;
      Os[i * AP + dd] = (f16)oacc[td][r];
    }
  __syncthreads();
  {
    const int i2 = tid >> 2, q4 = tid & 3;
    const int t = nchunk * 64 + i2;
    f16* dst = attn + ((size_t)(b * 4096 + t)) * 1024 + h * 64 + q4 * 16;
    const f16* src = &Os[i2 * AP + q4 * 16];
    *(f16x8*)(dst) = *(const f16x8*)(src);
    *(f16x8*)(dst + 8) = *(const f16x8*)(src + 8);
  }
}

// ---------------------------------------------------------------------------
// Pass 5: output projection GEMM (f16) — R6-proven 128x128 tile, grid (8,64).
// ---------------------------------------------------------------------------
__global__ __launch_bounds__(256) void k_gemm_out(
    const f16* __restrict__ A, const f16* __restrict__ B, float* __restrict__ out)
{
  __shared__ f16 As[128 * 64];
  __shared__ f16 Bs[128 * 64];
  const int tid = threadIdx.x;
  const int wave = tid >> 6, lane = tid & 63;
  const int quad = lane >> 4, l16 = lane & 15;
  const int n0 = blockIdx.x * 128;
  const int m0 = blockIdx.y * 128;
  const int wm = (wave >> 1) << 6, wn = (wave & 1) << 6;
  const int r8 = lane >> 3, c8 = lane & 7;
  const int sw = l16 & 7;
  const int srcoff = (c8 ^ r8) * 8;
  f32x4 acc[4][4] = {};

  for (int k0 = 0; k0 < 1024; k0 += 64) {
    __syncthreads();
#pragma unroll
    for (int it = 0; it < 4; ++it) {
      const int row = wave * 32 + it * 8 + r8;
      async_ld16(A + (size_t)(m0 + row) * 1024 + k0 + srcoff, As + row * 64 + c8 * 8);
      async_ld16(B + (size_t)(n0 + row) * 1024 + k0 + srcoff, Bs + row * 64 + c8 * 8);
    }
    __syncthreads();
#pragma unroll
    for (int ks = 0; ks < 64; ks += 32) {
      f16x8 af[4], bg[4];
#pragma unroll
      for (int mi = 0; mi < 4; ++mi)
        af[mi] = *(const f16x8*)&As[(wm + mi * 16 + l16) * 64 + ((((ks >> 3) + quad) ^ sw) << 3)];
#pragma unroll
      for (int ni = 0; ni < 4; ++ni)
        bg[ni] = *(const f16x8*)&Bs[(wn + ni * 16 + l16) * 64 + ((((ks >> 3) + quad) ^ sw) << 3)];
#pragma unroll
      for (int mi = 0; mi < 4; ++mi)
#pragma unroll
        for (int ni = 0; ni < 4; ++ni)
          acc[mi][ni] = __builtin_amdgcn_mfma_f32_16x16x32_f16(af[mi], bg[ni], acc[mi][ni], 0, 0, 0);
    }
  }
#pragma unroll
  for (int mi = 0; mi < 4; ++mi)
#pragma unroll
    for (int ni = 0; ni < 4; ++ni)
#pragma unroll
      for (int r = 0; r < 4; ++r) {
        const int m = m0 + wm + mi * 16 + quad * 4 + r;
        const int n = n0 + wn + ni * 16 + l16;
        out[(size_t)m * 1024 + n] = acc[mi][ni][r];
      }
}

// ---------------------------------------------------------------------------
extern "C" void kernel_launch(void* const* d_in, const int* in_sizes, int n_in,
                              void* d_out, int out_size, void* d_ws, size_t ws_size,
                              hipStream_t stream)
{
  const float* x = (const float*)d_in[0];
  const float* wqkv = (const float*)d_in[1];
  const float* wo = (const float*)d_in[2];
  float* out = (float*)d_out;
  char* ws = (char*)d_ws;

  bf16* xsplit = (bf16*)(ws);
  bf16* wsplit = (bf16*)(ws + 33554432);
  f16*  wo16   = (f16*)(ws + 46137344);
  bf16* Qws    = (bf16*)(ws + 48234496);
  bf16* Kws    = (bf16*)(ws + 65011712);
  bf16* Vws    = (bf16*)(ws + 81788928);
  short* ckv   = (short*)(ws + 98566144);   // 16,777,216 B (int16 chunk-KV / prefix)
  f16*  attn   = (f16*)(ws + 132120576);
  float* fin   = out + 8388608;

  k_convert<<<12288, 256, 0, stream>>>(x, wqkv, wo, xsplit, wsplit, wo16);
  k_gemm_qkv<<<dim3(24, 64), 256, 0, stream>>>(xsplit, wsplit, Qws, Kws, Vws);
  k_ckv<<<2048, 256, 0, stream>>>(Kws, Vws, ckv);
  k_scan<<<256, 256, 0, stream>>>(ckv, fin);
  k_attn<<<2048, 256, 0, stream>>>(Qws, Kws, Vws, ckv, attn);
  k_gemm_out<<<dim3(8, 64), 256, 0, stream>>>(attn, wo16, out);
}